// Round 10
// baseline (890.906 us; speedup 1.0000x reference)
//
#include <hip/hip_runtime.h>
#include <hip/hip_bf16.h>

static constexpr int HN = 32;     // Hemb == Hgcn == 32
static constexpr int NIN = 128;
static constexpr int CH1 = 8192;  // edges per hist/phase1 block

__device__ __forceinline__ float bf2f(unsigned short u) {
    union { unsigned int i; float f; } v;
    v.i = ((unsigned int)u) << 16;
    return v.f;
}
__device__ __forceinline__ unsigned short f2bf(float f) {
    union { float f; unsigned int i; } v; v.f = f;
    unsigned int r = (v.i + 0x7FFFu + ((v.i >> 16) & 1u)) >> 16;
    return (unsigned short)r;
}

// K1 (grid-fused): blocks [0,NBE) compute h = relu(x@Wemb+bemb) -> bf16;
// blocks [NBE, NBE+NBH) histogram col>>8 into bucket_cnt.
__global__ __launch_bounds__(256) void embed_hist_kernel(
    const float* __restrict__ x,
    const float* __restrict__ Wemb,
    const float* __restrict__ bemb,
    const int* __restrict__ col, int* __restrict__ bucket_cnt,
    unsigned short* __restrict__ h, int N, int E, int B, int NBE)
{
    const int tid = threadIdx.x;
    if ((int)blockIdx.x >= NBE) {
        __shared__ int hist[512];
        const int e0 = ((int)blockIdx.x - NBE) * CH1;
        for (int i = tid; i < B; i += 256) hist[i] = 0;
        __syncthreads();
        #pragma unroll
        for (int k = 0; k < CH1 / 256; ++k) {
            int e = e0 + k * 256 + tid;
            if (e < E) atomicAdd(&hist[col[e] >> 8], 1);
        }
        __syncthreads();
        for (int i = tid; i < B; i += 256)
            if (hist[i]) atomicAdd(&bucket_cnt[i], hist[i]);
        return;
    }

    __shared__ float We[NIN * HN];
    __shared__ float be[HN];
    __shared__ float xs[32][NIN];
    for (int i = tid; i < NIN * HN; i += 256) We[i] = Wemb[i];
    if (tid < HN) be[tid] = bemb[tid];

    const int n0 = blockIdx.x * 32;
    const float4* x4 = (const float4*)(x + (size_t)n0 * NIN);
    for (int i = tid; i < 32 * (NIN / 4); i += 256) {
        float4 u = x4[i];
        int base = i * 4, n = base >> 7, k = base & (NIN - 1);
        xs[n][k] = u.x; xs[n][k + 1] = u.y;
        xs[n][k + 2] = u.z; xs[n][k + 3] = u.w;
    }
    __syncthreads();

    const int f = tid & 31, ns = tid >> 5;
    float a0 = be[f], a1 = be[f], a2 = be[f], a3 = be[f];
    #pragma unroll 8
    for (int k = 0; k < NIN; ++k) {
        float w = We[k * HN + f];
        a0 += xs[ns +  0][k] * w;
        a1 += xs[ns +  8][k] * w;
        a2 += xs[ns + 16][k] * w;
        a3 += xs[ns + 24][k] * w;
    }
    if (n0 + ns      < N) h[(size_t)(n0 + ns     ) * HN + f] = f2bf(fmaxf(a0, 0.f));
    if (n0 + ns +  8 < N) h[(size_t)(n0 + ns +  8) * HN + f] = f2bf(fmaxf(a1, 0.f));
    if (n0 + ns + 16 < N) h[(size_t)(n0 + ns + 16) * HN + f] = f2bf(fmaxf(a2, 0.f));
    if (n0 + ns + 24 < N) h[(size_t)(n0 + ns + 24) * HN + f] = f2bf(fmaxf(a3, 0.f));
}

// K2: exclusive scan of bucket counts (B <= 512); init cursors.
__global__ __launch_bounds__(512) void bscan_kernel(
    const int* __restrict__ bucket_cnt, int* __restrict__ bucket_base,
    int* __restrict__ bucket_cursor, int B, int E)
{
    __shared__ int sc[512];
    __shared__ int orig[512];
    const int t = threadIdx.x;
    int v0 = (t < B) ? bucket_cnt[t] : 0;
    sc[t] = v0; orig[t] = v0;
    __syncthreads();
    for (int o = 1; o < 512; o <<= 1) {
        int v = (t >= o) ? sc[t - o] : 0;
        __syncthreads();
        sc[t] += v;
        __syncthreads();
    }
    if (t < B) {
        int ex = sc[t] - orig[t];
        bucket_base[t] = ex;
        bucket_cursor[t] = ex;
    }
    if (t == 0) bucket_base[B] = E;
}

// K3 (phase1): bucketize edges -> packed words (row<<8 | col&255).
__global__ __launch_bounds__(512) void phase1_kernel(
    const int* __restrict__ row, const int* __restrict__ col,
    int* __restrict__ bucket_cursor, int* __restrict__ bucketed, int E, int B)
{
    __shared__ int hist[512];
    __shared__ int gbase[512];
    const int t = threadIdx.x;
    const int e0 = blockIdx.x * CH1;

    for (int i = t; i < B; i += 512) hist[i] = 0;
    __syncthreads();
    #pragma unroll
    for (int k = 0; k < CH1 / 512; ++k) {
        int e = e0 + k * 512 + t;
        if (e < E) atomicAdd(&hist[col[e] >> 8], 1);
    }
    __syncthreads();
    for (int i = t; i < B; i += 512) {
        int hc = hist[i];
        gbase[i] = hc ? atomicAdd(&bucket_cursor[i], hc) : 0;
        hist[i] = 0;                      // becomes rank counter
    }
    __syncthreads();
    #pragma unroll
    for (int k = 0; k < CH1 / 512; ++k) {
        int e = e0 + k * 512 + t;
        if (e < E) {
            int c = col[e], r = row[e];
            int b = c >> 8;
            int lr = atomicAdd(&hist[b], 1);
            bucketed[gbase[b] + lr] = (r << 8) | (c & 255);
        }
    }
}

// K4 (phase2, fused): per-bucket CSR placement + rowptr + hws = dis*(h@Wgcn).
__global__ __launch_bounds__(256) void phase2_kernel(
    const int* __restrict__ bucketed, const int* __restrict__ bucket_base,
    const unsigned short* __restrict__ h, const float* __restrict__ Wgcn,
    int* __restrict__ rowptr, int* __restrict__ csr_src,
    unsigned short* __restrict__ hws, int N, int E)
{
    __shared__ int cnt[256];
    __shared__ int sc[256];
    __shared__ int base[256];
    __shared__ int degs[256];
    __shared__ float hsn[256 * HN];   // 32 KB
    __shared__ float Wg[HN * HN];     // 4 KB
    const int t = threadIdx.x, b = blockIdx.x;
    const int s0 = bucket_base[b], s1 = bucket_base[b + 1];
    const int node0 = b << 8;
    cnt[t] = 0;
    for (int i = t; i < HN * HN; i += 256) Wg[i] = Wgcn[i];
    __syncthreads();
    for (int i = s0 + t; i < s1; i += 256)
        atomicAdd(&cnt[bucketed[i] & 255], 1);
    __syncthreads();
    int myc = cnt[t];
    degs[t] = myc;
    sc[t] = myc;
    __syncthreads();
    for (int o = 1; o < 256; o <<= 1) {
        int v = (t >= o) ? sc[t - o] : 0;
        __syncthreads();
        sc[t] += v;
        __syncthreads();
    }
    int ex = s0 + sc[t] - myc;            // exclusive prefix within bucket
    base[t] = ex;
    int node = node0 + t;
    if (node < N) rowptr[node] = ex;
    if (b == (int)gridDim.x - 1 && t == 0) rowptr[N] = E;
    cnt[t] = 0;
    const int nodes = (N - node0 < 256) ? (N - node0) : 256;
    for (int i = t; i < nodes * HN; i += 256)
        hsn[i] = bf2f(h[(size_t)node0 * HN + i]);
    __syncthreads();
    for (int i = s0 + t; i < s1; i += 256) {
        int w = bucketed[i];
        int lc = w & 255;
        int pos = base[lc] + atomicAdd(&cnt[lc], 1);
        csr_src[pos] = w >> 8;
    }
    // fused hws compute: 8 nodes x 32 features per pass, broadcast LDS reads
    const int f = t & 31;
    #pragma unroll 4
    for (int g = 0; g < 32; ++g) {
        int n = g * 8 + (t >> 5);
        int v = node0 + n;
        if (v < N) {
            float acc = 0.f;
            #pragma unroll
            for (int k = 0; k < HN; ++k) acc += hsn[n * HN + k] * Wg[k * HN + f];
            float dis = rsqrtf((float)degs[n] + 1.0f);
            hws[(size_t)v * HN + f] = f2bf(dis * acc);
        }
    }
}

// K5 (passB): fused gather pass, online softmax, bf16 gathers, atomicMax amax.
__global__ __launch_bounds__(256) void passB_kernel(
    const unsigned short* __restrict__ h, const unsigned short* __restrict__ hws,
    const int* __restrict__ csr_src, const int* __restrict__ rowptr,
    const float* __restrict__ tarr, const float* __restrict__ bgcn,
    float* __restrict__ outr, float* __restrict__ outz,
    float* __restrict__ out0_ml, float* __restrict__ denout,
    int* __restrict__ amax_bits, int N)
{
    const int tid = threadIdx.x;
    const int lane = tid & 31;
    const int sub = lane >> 3;
    const int j = lane & 7;
    const int v = blockIdx.x * 8 + (tid >> 5);
    if (v >= N) return;

    const ushort4* h4 = (const ushort4*)h;
    const ushort4* w4 = (const ushort4*)hws;
    ushort4 hu = h4[(size_t)v * 8 + j];
    ushort4 wu = w4[(size_t)v * 8 + j];
    float4 hv = make_float4(bf2f(hu.x), bf2f(hu.y), bf2f(hu.z), bf2f(hu.w));
    float4 wsv = make_float4(bf2f(wu.x), bf2f(wu.y), bf2f(wu.z), bf2f(wu.w));
    const int s = rowptr[v], e2 = rowptr[v + 1];

    float m = -1e30f, den = 0.f, num = 0.f;
    float ax = 0.f, ay = 0.f, az = 0.f, aw = 0.f;
    int i = s + sub;
    int r = (i < e2) ? csr_src[i] : 0;
    while (i < e2) {
        int in = i + 4;
        int rn = (in < e2) ? csr_src[in] : 0;
        ushort4 hru = h4[(size_t)r * 8 + j];
        ushort4 wru = w4[(size_t)r * 8 + j];
        float tr = tarr[r];
        float p = hv.x * bf2f(hru.x) + hv.y * bf2f(hru.y)
                + hv.z * bf2f(hru.z) + hv.w * bf2f(hru.w);
        p += __shfl_xor(p, 1, 32);
        p += __shfl_xor(p, 2, 32);
        p += __shfl_xor(p, 4, 32);
        float mn = fmaxf(m, p);
        float corr = __expf(m - mn);
        float a = __expf(p - mn);
        den = den * corr + a;
        num = num * corr + a * tr;
        m = mn;
        ax += bf2f(wru.x); ay += bf2f(wru.y);
        az += bf2f(wru.z); aw += bf2f(wru.w);
        i = in; r = rn;
    }
    #pragma unroll
    for (int o = 8; o <= 16; o <<= 1) {
        float mo = __shfl_xor(m, o, 32);
        float dno = __shfl_xor(den, o, 32);
        float nmo = __shfl_xor(num, o, 32);
        float mn = fmaxf(m, mo);
        float ca = __expf(m - mn), cb = __expf(mo - mn);
        den = den * ca + dno * cb;
        num = num * ca + nmo * cb;
        m = mn;
        ax += __shfl_xor(ax, o, 32);
        ay += __shfl_xor(ay, o, 32);
        az += __shfl_xor(az, o, 32);
        aw += __shfl_xor(aw, o, 32);
    }

    float dv = rsqrtf((float)(e2 - s) + 1.0f);
    float4 rep;
    rep.x = hv.x + fmaxf(dv * (ax + wsv.x) + bgcn[4 * j + 0], 0.f);
    rep.y = hv.y + fmaxf(dv * (ay + wsv.y) + bgcn[4 * j + 1], 0.f);
    rep.z = hv.z + fmaxf(dv * (az + wsv.z) + bgcn[4 * j + 2], 0.f);
    rep.w = hv.w + fmaxf(dv * (aw + wsv.w) + bgcn[4 * j + 3], 0.f);
    if (sub == 0)
        ((float4*)outr)[(size_t)v * 8 + j] = rep;
    if (lane == 0) {
        outz[v]    = num / fmaxf(den, 1e-37f);
        out0_ml[v] = m;
        denout[v]  = den;
        // all dots >= 0 (h = relu >= 0) and amax pre-zeroed, so int-bits
        // atomicMax is order-correct; deg-0 nodes (m=-1e30 < 0) lose.
        atomicMax(amax_bits, __float_as_int(m));
    }
}

// K6: exact epsilon correction + FF head.
__global__ __launch_bounds__(256) void final_kernel(
    const float* __restrict__ rep_in,
    const float* __restrict__ tarr,
    const float* __restrict__ amax, const float* __restrict__ denarr,
    const float* __restrict__ W1, const float* __restrict__ b1,
    const float* __restrict__ W2, const float* __restrict__ b2,
    float* __restrict__ out0, float* __restrict__ outz, int N)
{
    __shared__ float W1s[34 * HN];
    __shared__ float b1s[HN], W2s[HN];
    __shared__ float b2s;
    const int tid = threadIdx.x;
    for (int i = tid; i < 34 * HN; i += 256) W1s[i] = W1[i];
    if (tid < HN) {
        b1s[tid] = b1[tid];
        W2s[tid] = W2[tid];
    }
    if (tid == 0) b2s = b2[0];
    __syncthreads();

    const int lane = tid & 31;
    const int v = blockIdx.x * 8 + (tid >> 5);
    if (v >= N) return;

    float rep = rep_in[(size_t)v * HN + lane];
    float ml  = out0[v];
    float den = denarr[v];
    float zh  = outz[v];
    float am  = amax[0];
    float term = (1e-8f / den) * expf(am - ml);
    float z = zh / (1.0f + term);
    float tv = tarr[v];

    float acc = b1s[lane] + tv * W1s[32 * HN + lane] + z * W1s[33 * HN + lane];
    #pragma unroll
    for (int k = 0; k < HN; ++k)
        acc += __shfl(rep, k, 32) * W1s[k * HN + lane];
    float f1 = fmaxf(acc, 0.f);
    float o = f1 * W2s[lane];
    #pragma unroll
    for (int m = 16; m; m >>= 1) o += __shfl_xor(o, m, 32);

    if (lane == 0) {
        out0[v] = o + b2s;
        outz[v] = z;
    }
}

extern "C" void kernel_launch(void* const* d_in, const int* in_sizes, int n_in,
                              void* d_out, int out_size, void* d_ws, size_t ws_size,
                              hipStream_t stream)
{
    const int N = out_size / 34;   // out[N] + rep[N*32] + z[N]
    const int E = in_sizes[2];

    const float* x    = (const float*)d_in[0];
    const float* t    = (const float*)d_in[1];
    const int* row    = (const int*)d_in[2];
    const int* col    = (const int*)d_in[3];
    const float* Wemb = (const float*)d_in[4];
    const float* bemb = (const float*)d_in[5];
    const float* Wgcn = (const float*)d_in[6];
    const float* bgcn = (const float*)d_in[7];
    const float* W1   = (const float*)d_in[8];
    const float* b1   = (const float*)d_in[9];
    const float* W2   = (const float*)d_in[10];
    const float* b2   = (const float*)d_in[11];

    const int B   = (N + 255) >> 8;       // coarse buckets (<=512)
    const int NBE = (N + 31) / 32;        // embed blocks
    const int NBH = (E + CH1 - 1) / CH1;  // hist/phase1 blocks

    // ws (~39.2 MB): h(bf16) | hws(bf16) | bucketed | csr_src | rowptr | den
    //                | bucket_cnt | amax | bucket_base | bucket_cursor
    char* wsb = (char*)d_ws;
    size_t off = 0;
    unsigned short* h   = (unsigned short*)(wsb + off); off += (size_t)N * HN * 2;
    unsigned short* hws = (unsigned short*)(wsb + off); off += (size_t)N * HN * 2;
    int*   bucketed = (int*)(wsb + off);   off += (size_t)E * 4;
    int*   csr_src  = (int*)(wsb + off);   off += (size_t)E * 4;
    int*   rowptr   = (int*)(wsb + off);   off += (size_t)(N + 1) * 4;
    float* den      = (float*)(wsb + off); off += (size_t)N * 4;
    int*   bucket_cnt = (int*)(wsb + off); off += (size_t)B * 4;
    float* amax     = (float*)(wsb + off); off += 4;   // adjacent: one memset
    int*   bucket_base   = (int*)(wsb + off); off += (size_t)(B + 1) * 4;
    int*   bucket_cursor = (int*)(wsb + off); off += (size_t)B * 4;

    hipMemsetAsync(bucket_cnt, 0, (size_t)(B + 1) * 4, stream);  // cnt + amax

    embed_hist_kernel<<<NBE + NBH, 256, 0, stream>>>(
        x, Wemb, bemb, col, bucket_cnt, h, N, E, B, NBE);
    bscan_kernel<<<1, 512, 0, stream>>>(bucket_cnt, bucket_base,
                                        bucket_cursor, B, E);
    phase1_kernel<<<NBH, 512, 0, stream>>>(row, col, bucket_cursor,
                                           bucketed, E, B);
    phase2_kernel<<<B, 256, 0, stream>>>(bucketed, bucket_base, h, Wgcn,
                                         rowptr, csr_src, hws, N, E);

    float* outp = (float*)d_out;
    float* out0 = outp;
    float* outr = outp + N;
    float* outz = outp + (size_t)N * 33;

    passB_kernel<<<(N + 7) / 8, 256, 0, stream>>>(
        h, hws, csr_src, rowptr, t, bgcn, outr, outz, out0, den,
        (int*)amax, N);
    final_kernel<<<(N + 7) / 8, 256, 0, stream>>>(
        outr, t, amax, den, W1, b1, W2, b2, out0, outz, N);
}